// Round 4
// baseline (430.282 us; speedup 1.0000x reference)
//
#include <hip/hip_runtime.h>
#include <stdint.h>

#define IN_FEATS 128
#define OUT_FEATS 256
#define TOPK 32
#define BM 128
#define BN 256     /* full N in one block: A-tile staged exactly once */
#define BK 64      /* K-step: 64 bf16 = 128 B row = 8x 16B chunks */
#define KTOT 256

typedef float f32x4 __attribute__((ext_vector_type(4)));
typedef short bf16x8 __attribute__((ext_vector_type(8)));

__device__ __forceinline__ unsigned short f2bf(float x) {
    unsigned u = __float_as_uint(x);
    u += 0x7FFFu + ((u >> 16) & 1u);   // round-to-nearest-even
    return (unsigned short)(u >> 16);
}

// async 16B global -> LDS (linear dest: wave-uniform base + lane*16)
__device__ __forceinline__ void gload16(const void* g, void* l) {
    __builtin_amdgcn_global_load_lds(
        (const __attribute__((address_space(1))) unsigned*)g,
        (__attribute__((address_space(3))) unsigned*)l, 16, 0, 0);
}

// K1: scatter top-k into dense bf16 x_sparse [N,128], 4 nodes/block.
// Duplicate indices ACCUMULATE (reference .add) -> atomicAdd in LDS.
// Fused: feat f32->bf16 convert into Acat[:,128:256] (coalesced streaming),
// piggybacked here because this kernel is latency-bound with idle BW.
__global__ __launch_bounds__(256) void k_scatter(
    const float* __restrict__ vals, const int* __restrict__ idxs,
    const float* __restrict__ feat,
    unsigned short* __restrict__ xsp, unsigned short* __restrict__ Acat,
    int n_nodes) {
    __shared__ float lds[4 * IN_FEATS];
    int t = threadIdx.x;
    int n0 = blockIdx.x * 4;
    lds[t] = 0.f;
    lds[t + 256] = 0.f;
    __syncthreads();
    if (t < 4 * TOPK) {
        int h = t >> 5;          // which of the 4 nodes
        int k = t & 31;
        int n = n0 + h;
        if (n < n_nodes) {
            float v = vals[(size_t)n * TOPK + k];
            int ix = idxs[(size_t)n * TOPK + k] & 127;
            atomicAdd(&lds[h * IN_FEATS + ix], v);
        }
    }
    __syncthreads();
    // 64 threads per node, 2 consecutive feats each -> packed u32 stores
    int h2 = t >> 6;
    int f2 = (t & 63) * 2;
    int n = n0 + h2;
    if (n < n_nodes) {
        unsigned lo = f2bf(lds[h2 * IN_FEATS + f2]);
        unsigned hi = f2bf(lds[h2 * IN_FEATS + f2 + 1]);
        *(unsigned*)(xsp + (size_t)n * IN_FEATS + f2) = lo | (hi << 16);
        float2 fv = *(const float2*)(feat + (size_t)n * IN_FEATS + f2);
        unsigned pk = (unsigned)f2bf(fv.x) | ((unsigned)f2bf(fv.y) << 16);
        *(unsigned*)(Acat + (size_t)n * KTOT + IN_FEATS + f2) = pk;
    }
}

// Kw: build W^T bf16 [256 outs][256 ks], rows = output col, concat K = [W_neigh; W_self]
__global__ void k_weights(const float* __restrict__ Wn, const float* __restrict__ Ws,
                          unsigned short* __restrict__ WT) {
    int idx = blockIdx.x * 256 + threadIdx.x;   // 0..65535
    int n = idx >> 8;
    int k = idx & 255;
    float v = (k < IN_FEATS) ? Wn[(size_t)k * OUT_FEATS + n]
                             : Ws[(size_t)(k - IN_FEATS) * OUT_FEATS + n];
    WT[idx] = f2bf(v);
}

// K2: mean aggregation -> Acat[node][0:128]. One wave per node, 4 nodes/block.
// Edge range found by per-wave binary search on sorted row[] (replaces the
// k_indptr kernel: 2x ~21 wave-uniform L2/L3-hit loads, absorbed in this
// kernel's latency slack). lane = eg*16 + fi: 16 lanes x 16B cover one bf16
// row; 4 edge groups x 4-deep unroll -> 16 gathers in flight (avg degree 16).
// Register accumulate only -- no LDS atomics (round-2 lesson: LDS scatter-add
// serializes 4x worse than the extra gather bytes cost).
__global__ __launch_bounds__(256) void k_aggregate(
    const unsigned short* __restrict__ xsp,
    const int* __restrict__ row, const int* __restrict__ col,
    unsigned short* __restrict__ Acat, int n_nodes, int n_edges) {
    int t = threadIdx.x;
    int node = blockIdx.x * 4 + (t >> 6);
    if (node >= n_nodes) return;
    int lane = t & 63;
    int eg = lane >> 4, fi = lane & 15;

    // e0 = lower_bound(row, node); e1 = lower_bound(row, node+1)
    int lo = 0, hi = n_edges;
    while (lo < hi) { int mid = (lo + hi) >> 1; if (row[mid] < node) lo = mid + 1; else hi = mid; }
    int e0 = lo;
    hi = n_edges;
    while (lo < hi) { int mid = (lo + hi) >> 1; if (row[mid] <= node) lo = mid + 1; else hi = mid; }
    int e1 = lo;

    float acc[8] = {0.f, 0.f, 0.f, 0.f, 0.f, 0.f, 0.f, 0.f};
    int elast = (e1 > e0) ? (e1 - 1) : e0;
    for (int base = e0; base < e1; base += 16) {
        float s[4];
        int c[4];
        uint4 u[4];
#pragma unroll
        for (int j = 0; j < 4; ++j) {
            int ee = base + j * 4 + eg;
            s[j] = (ee < e1) ? 1.f : 0.f;
            c[j] = col[ee < elast ? ee : elast];
        }
#pragma unroll
        for (int j = 0; j < 4; ++j)
            u[j] = *(const uint4*)(xsp + (size_t)c[j] * IN_FEATS + fi * 8);
#pragma unroll
        for (int j = 0; j < 4; ++j) {
            unsigned p[4] = {u[j].x, u[j].y, u[j].z, u[j].w};
#pragma unroll
            for (int i = 0; i < 4; ++i) {
                acc[2 * i]     = fmaf(s[j], __uint_as_float(p[i] << 16), acc[2 * i]);
                acc[2 * i + 1] = fmaf(s[j], __uint_as_float(p[i] & 0xFFFF0000u), acc[2 * i + 1]);
            }
        }
    }
    // reduce across the 4 edge subgroups (stride 16, 32)
#pragma unroll
    for (int i = 0; i < 8; ++i) {
        acc[i] += __shfl_down(acc[i], 16, 64);
        acc[i] += __shfl_down(acc[i], 32, 64);
    }
    if (eg == 0) {
        int cnt = e1 - e0;
        float inv = 1.0f / (float)(cnt > 0 ? cnt : 1);  // == 1/max(deg,1)
        unsigned o[4];
#pragma unroll
        for (int i = 0; i < 4; ++i) {
            unsigned lo2 = f2bf(acc[2 * i] * inv);
            unsigned hi2 = f2bf(acc[2 * i + 1] * inv);
            o[i] = lo2 | (hi2 << 16);
        }
        *(uint4*)(Acat + (size_t)node * KTOT + fi * 8) = *(uint4*)&o[0];
    }
}

// K3: rst = Acat @ WT^T + bias.  M=n_nodes, K=256, N=256, all-bf16 A/B.
// BM=128 x BN=256 (full N per block -> A staged exactly once; halves A reads
// vs the 2-N-tile grid). 512 threads = 8 waves in a 2x4 grid, each wave a
// 64x64 output tile of 16x16x32 MFMAs. global_load_lds width-16 staging,
// LDS LINEAR (required by gload_lds); bank spread via chunk swizzle
// q ^= (row&7) applied identically to global SOURCE and ds_read (rule #21).
__global__ __launch_bounds__(512) void k_gemm(
    const unsigned short* __restrict__ Acat,  // [N,256] bf16
    const unsigned short* __restrict__ WT,    // [256][256] bf16, WT[n][k]
    const float* __restrict__ bias,
    float* __restrict__ out, int n_nodes) {
    __shared__ __align__(16) unsigned short Ash[BM * BK];  // 16 KB
    __shared__ __align__(16) unsigned short Bsh[BN * BK];  // 32 KB
    int t = threadIdx.x;
    int m0 = blockIdx.x * BM;
    int lane = t & 63;
    int w = t >> 6;           // 0..7
    int wr = w >> 2, wc = w & 3;
    int lrow = lane & 15, quad = lane >> 4;

    f32x4 acc[4][4];
#pragma unroll
    for (int i = 0; i < 4; ++i)
#pragma unroll
        for (int j = 0; j < 4; ++j)
            acc[i][j] = (f32x4){0.f, 0.f, 0.f, 0.f};

    for (int kk = 0; kk < KTOT; kk += BK) {
        // ---- stage A (1024 chunks, 2/thread) and B (2048 chunks, 4/thread) ----
#pragma unroll
        for (int p = 0; p < 2; ++p) {
            int c = p * 512 + t;
            int rowi = c >> 3;
            int q = (c & 7) ^ (rowi & 7);    // inverse-swizzled global source
            int nodeA = m0 + rowi;
            if (nodeA >= n_nodes) nodeA = n_nodes - 1;   // clamp, in-bounds read
            gload16(Acat + (size_t)nodeA * KTOT + kk + q * 8, &Ash[(size_t)c * 8]);
        }
#pragma unroll
        for (int p = 0; p < 4; ++p) {
            int c = p * 512 + t;
            int rowi = c >> 3;               // 0..255 = global n
            int q = (c & 7) ^ (rowi & 7);
            gload16(WT + (size_t)rowi * KTOT + kk + q * 8, &Bsh[(size_t)c * 8]);
        }
        __syncthreads();

#pragma unroll
        for (int ks = 0; ks < 2; ++ks) {     // two 16x16x32 K-substeps per BK=64
            bf16x8 af[4], bfr[4];
#pragma unroll
            for (int mi = 0; mi < 4; ++mi) {
                int r = wr * 64 + mi * 16 + lrow;
                int q = (ks * 4 + quad) ^ (r & 7);       // swizzled read
                af[mi] = *(const bf16x8*)&Ash[(r * 8 + q) * 8];
            }
#pragma unroll
            for (int ni = 0; ni < 4; ++ni) {
                int r = wc * 64 + ni * 16 + lrow;        // 0..255
                int q = (ks * 4 + quad) ^ (r & 7);
                bfr[ni] = *(const bf16x8*)&Bsh[(r * 8 + q) * 8];
            }
#pragma unroll
            for (int mi = 0; mi < 4; ++mi)
#pragma unroll
                for (int ni = 0; ni < 4; ++ni)
                    acc[mi][ni] = __builtin_amdgcn_mfma_f32_16x16x32_bf16(
                        af[mi], bfr[ni], acc[mi][ni], 0, 0, 0);
        }
        __syncthreads();
    }

    // epilogue: C/D layout col=lane&15, row=quad*4+reg
#pragma unroll
    for (int mi = 0; mi < 4; ++mi) {
        int gm = m0 + wr * 64 + mi * 16 + quad * 4;
#pragma unroll
        for (int ni = 0; ni < 4; ++ni) {
            int go = wc * 64 + ni * 16 + lrow;
            float b = bias[go];
#pragma unroll
            for (int r = 0; r < 4; ++r) {
                int node = gm + r;
                if (node < n_nodes)
                    out[(size_t)node * OUT_FEATS + go] = acc[mi][ni][r] + b;
            }
        }
    }
}

extern "C" void kernel_launch(void* const* d_in, const int* in_sizes, int n_in,
                              void* d_out, int out_size, void* d_ws, size_t ws_size,
                              hipStream_t stream) {
    const float* feat = (const float*)d_in[0];
    const float* tkv  = (const float*)d_in[1];
    const int*   tki  = (const int*)d_in[2];
    const int*   row  = (const int*)d_in[3];
    const int*   col  = (const int*)d_in[4];
    const float* Wn   = (const float*)d_in[6];
    const float* Ws   = (const float*)d_in[7];
    const float* bias = (const float*)d_in[8];
    float* out = (float*)d_out;

    int n_nodes = in_sizes[5];
    int n_edges = in_sizes[3];

    // ws layout: xsp bf16 [N,128] | Acat bf16 [N,256] | WT bf16 [256,256]
    unsigned short* xsp  = (unsigned short*)d_ws;
    unsigned short* Acat = xsp + (size_t)n_nodes * IN_FEATS;
    unsigned short* WT   = Acat + (size_t)n_nodes * KTOT;

    k_scatter<<<(n_nodes + 3) / 4, 256, 0, stream>>>(tkv, tki, feat, xsp, Acat, n_nodes);
    k_weights<<<256, 256, 0, stream>>>(Wn, Ws, WT);
    k_aggregate<<<(n_nodes + 3) / 4, 256, 0, stream>>>(xsp, row, col, Acat, n_nodes, n_edges);
    k_gemm<<<(n_nodes + BM - 1) / BM, 512, 0, stream>>>(Acat, WT, bias, out, n_nodes);
}

// Round 5
// 291.338 us; speedup vs baseline: 1.4769x; 1.4769x over previous
//
#include <hip/hip_runtime.h>
#include <stdint.h>

#define IN_FEATS 128
#define OUT_FEATS 256
#define TOPK 32
#define BM 128
#define BN 256     /* full N in one block: A-tile staged exactly once */
#define BK 64      /* K-step: 64 bf16 = 128 B row = 8x 16B chunks */
#define KTOT 256

typedef float f32x4 __attribute__((ext_vector_type(4)));
typedef short bf16x8 __attribute__((ext_vector_type(8)));

__device__ __forceinline__ unsigned short f2bf(float x) {
    unsigned u = __float_as_uint(x);
    u += 0x7FFFu + ((u >> 16) & 1u);   // round-to-nearest-even
    return (unsigned short)(u >> 16);
}

// async 16B global -> LDS (linear dest: wave-uniform base + lane*16)
__device__ __forceinline__ void gload16(const void* g, void* l) {
    __builtin_amdgcn_global_load_lds(
        (const __attribute__((address_space(1))) unsigned*)g,
        (__attribute__((address_space(3))) unsigned*)l, 16, 0, 0);
}

// K1: scatter top-k into dense bf16 x_sparse [N,128], 4 nodes/block.
// Duplicate indices ACCUMULATE (reference .add) -> atomicAdd in LDS.
// Fused: feat f32->bf16 convert into Acat[:,128:256] (coalesced streaming),
// piggybacked here because this kernel is latency-bound with idle BW.
__global__ __launch_bounds__(256) void k_scatter(
    const float* __restrict__ vals, const int* __restrict__ idxs,
    const float* __restrict__ feat,
    unsigned short* __restrict__ xsp, unsigned short* __restrict__ Acat,
    int n_nodes) {
    __shared__ float lds[4 * IN_FEATS];
    int t = threadIdx.x;
    int n0 = blockIdx.x * 4;
    lds[t] = 0.f;
    lds[t + 256] = 0.f;
    __syncthreads();
    if (t < 4 * TOPK) {
        int h = t >> 5;          // which of the 4 nodes
        int k = t & 31;
        int n = n0 + h;
        if (n < n_nodes) {
            float v = vals[(size_t)n * TOPK + k];
            int ix = idxs[(size_t)n * TOPK + k] & 127;
            atomicAdd(&lds[h * IN_FEATS + ix], v);
        }
    }
    __syncthreads();
    // 64 threads per node, 2 consecutive feats each -> packed u32 stores
    int h2 = t >> 6;
    int f2 = (t & 63) * 2;
    int n = n0 + h2;
    if (n < n_nodes) {
        unsigned lo = f2bf(lds[h2 * IN_FEATS + f2]);
        unsigned hi = f2bf(lds[h2 * IN_FEATS + f2 + 1]);
        *(unsigned*)(xsp + (size_t)n * IN_FEATS + f2) = lo | (hi << 16);
        float2 fv = *(const float2*)(feat + (size_t)n * IN_FEATS + f2);
        unsigned pk = (unsigned)f2bf(fv.x) | ((unsigned)f2bf(fv.y) << 16);
        *(unsigned*)(Acat + (size_t)n * KTOT + IN_FEATS + f2) = pk;
    }
}

// Kw: build W^T bf16 [256 outs][256 ks], rows = output col, concat K = [W_neigh; W_self]
__global__ void k_weights(const float* __restrict__ Wn, const float* __restrict__ Ws,
                          unsigned short* __restrict__ WT) {
    int idx = blockIdx.x * 256 + threadIdx.x;   // 0..65535
    int n = idx >> 8;
    int k = idx & 255;
    float v = (k < IN_FEATS) ? Wn[(size_t)k * OUT_FEATS + n]
                             : Ws[(size_t)(k - IN_FEATS) * OUT_FEATS + n];
    WT[idx] = f2bf(v);
}

// Ki: build indptr[N+1] from sorted row[] (edge-parallel, writes gap ranges).
// Round-4 lesson: this O(1)-depth streaming dispatch (~5-10us) beats a
// per-wave binary search (42 dependent loads/wave = ~150us of latency).
__global__ void k_indptr(const int* __restrict__ row, int* __restrict__ indptr,
                         int n_nodes, int n_edges) {
    int e = blockIdx.x * 256 + threadIdx.x;
    if (e >= n_edges) return;
    int r = row[e];
    int rp = (e == 0) ? -1 : row[e - 1];
    for (int x = rp + 1; x <= r; ++x) indptr[x] = e;
    if (e == n_edges - 1)
        for (int x = r + 1; x <= n_nodes; ++x) indptr[x] = n_edges;
}

// K2: mean aggregation -> Acat[node][0:128]. One wave per node, 4 nodes/block.
// lane = eg*16 + fi: 16 lanes x 16B cover one bf16 feature row; 4 edge groups
// x 4-deep unroll -> 16 dense-row gathers in flight per wave (avg degree 16).
// Register accumulate only -- no LDS atomics (round-2 lesson: LDS scatter-add
// serializes 4x worse than the extra gather bytes cost).
__global__ __launch_bounds__(256) void k_aggregate(
    const unsigned short* __restrict__ xsp,
    const int* __restrict__ indptr, const int* __restrict__ col,
    unsigned short* __restrict__ Acat, int n_nodes) {
    int t = threadIdx.x;
    int node = blockIdx.x * 4 + (t >> 6);
    if (node >= n_nodes) return;
    int lane = t & 63;
    int eg = lane >> 4, fi = lane & 15;
    int e0 = indptr[node], e1 = indptr[node + 1];

    float acc[8] = {0.f, 0.f, 0.f, 0.f, 0.f, 0.f, 0.f, 0.f};
    int elast = (e1 > e0) ? (e1 - 1) : e0;
    for (int base = e0; base < e1; base += 16) {
        float s[4];
        int c[4];
        uint4 u[4];
#pragma unroll
        for (int j = 0; j < 4; ++j) {
            int ee = base + j * 4 + eg;
            s[j] = (ee < e1) ? 1.f : 0.f;
            c[j] = col[ee < elast ? ee : elast];
        }
#pragma unroll
        for (int j = 0; j < 4; ++j)
            u[j] = *(const uint4*)(xsp + (size_t)c[j] * IN_FEATS + fi * 8);
#pragma unroll
        for (int j = 0; j < 4; ++j) {
            unsigned p[4] = {u[j].x, u[j].y, u[j].z, u[j].w};
#pragma unroll
            for (int i = 0; i < 4; ++i) {
                acc[2 * i]     = fmaf(s[j], __uint_as_float(p[i] << 16), acc[2 * i]);
                acc[2 * i + 1] = fmaf(s[j], __uint_as_float(p[i] & 0xFFFF0000u), acc[2 * i + 1]);
            }
        }
    }
    // reduce across the 4 edge subgroups (stride 16, 32)
#pragma unroll
    for (int i = 0; i < 8; ++i) {
        acc[i] += __shfl_down(acc[i], 16, 64);
        acc[i] += __shfl_down(acc[i], 32, 64);
    }
    if (eg == 0) {
        int cnt = e1 - e0;
        float inv = 1.0f / (float)(cnt > 0 ? cnt : 1);  // == 1/max(deg,1)
        unsigned o[4];
#pragma unroll
        for (int i = 0; i < 4; ++i) {
            unsigned lo = f2bf(acc[2 * i] * inv);
            unsigned hi = f2bf(acc[2 * i + 1] * inv);
            o[i] = lo | (hi << 16);
        }
        *(uint4*)(Acat + (size_t)node * KTOT + fi * 8) = *(uint4*)&o[0];
    }
}

// K3: rst = Acat @ WT^T + bias.  M=n_nodes, K=256, N=256, all-bf16 A/B.
// BM=128 x BN=256 (full N per block -> A staged exactly once; halves A reads
// vs the 2-N-tile grid). 512 threads = 8 waves in a 2x4 grid, each wave a
// 64x64 output tile of 16x16x32 MFMAs. global_load_lds width-16 staging,
// LDS LINEAR (required by gload_lds); bank spread via chunk swizzle
// q ^= (row&7) applied identically to global SOURCE and ds_read (rule #21).
__global__ __launch_bounds__(512) void k_gemm(
    const unsigned short* __restrict__ Acat,  // [N,256] bf16
    const unsigned short* __restrict__ WT,    // [256][256] bf16, WT[n][k]
    const float* __restrict__ bias,
    float* __restrict__ out, int n_nodes) {
    __shared__ __align__(16) unsigned short Ash[BM * BK];  // 16 KB
    __shared__ __align__(16) unsigned short Bsh[BN * BK];  // 32 KB
    int t = threadIdx.x;
    int m0 = blockIdx.x * BM;
    int lane = t & 63;
    int w = t >> 6;           // 0..7
    int wr = w >> 2, wc = w & 3;
    int lrow = lane & 15, quad = lane >> 4;

    f32x4 acc[4][4];
#pragma unroll
    for (int i = 0; i < 4; ++i)
#pragma unroll
        for (int j = 0; j < 4; ++j)
            acc[i][j] = (f32x4){0.f, 0.f, 0.f, 0.f};

    for (int kk = 0; kk < KTOT; kk += BK) {
        // ---- stage A (1024 chunks, 2/thread) and B (2048 chunks, 4/thread) ----
#pragma unroll
        for (int p = 0; p < 2; ++p) {
            int c = p * 512 + t;
            int rowi = c >> 3;
            int q = (c & 7) ^ (rowi & 7);    // inverse-swizzled global source
            int nodeA = m0 + rowi;
            if (nodeA >= n_nodes) nodeA = n_nodes - 1;   // clamp, in-bounds read
            gload16(Acat + (size_t)nodeA * KTOT + kk + q * 8, &Ash[(size_t)c * 8]);
        }
#pragma unroll
        for (int p = 0; p < 4; ++p) {
            int c = p * 512 + t;
            int rowi = c >> 3;               // 0..255 = global n
            int q = (c & 7) ^ (rowi & 7);
            gload16(WT + (size_t)rowi * KTOT + kk + q * 8, &Bsh[(size_t)c * 8]);
        }
        __syncthreads();

#pragma unroll
        for (int ks = 0; ks < 2; ++ks) {     // two 16x16x32 K-substeps per BK=64
            bf16x8 af[4], bfr[4];
#pragma unroll
            for (int mi = 0; mi < 4; ++mi) {
                int r = wr * 64 + mi * 16 + lrow;
                int q = (ks * 4 + quad) ^ (r & 7);       // swizzled read
                af[mi] = *(const bf16x8*)&Ash[(r * 8 + q) * 8];
            }
#pragma unroll
            for (int ni = 0; ni < 4; ++ni) {
                int r = wc * 64 + ni * 16 + lrow;        // 0..255
                int q = (ks * 4 + quad) ^ (r & 7);
                bfr[ni] = *(const bf16x8*)&Bsh[(r * 8 + q) * 8];
            }
#pragma unroll
            for (int mi = 0; mi < 4; ++mi)
#pragma unroll
                for (int ni = 0; ni < 4; ++ni)
                    acc[mi][ni] = __builtin_amdgcn_mfma_f32_16x16x32_bf16(
                        af[mi], bfr[ni], acc[mi][ni], 0, 0, 0);
        }
        __syncthreads();
    }

    // epilogue: C/D layout col=lane&15, row=quad*4+reg
#pragma unroll
    for (int mi = 0; mi < 4; ++mi) {
        int gm = m0 + wr * 64 + mi * 16 + quad * 4;
#pragma unroll
        for (int ni = 0; ni < 4; ++ni) {
            int go = wc * 64 + ni * 16 + lrow;
            float b = bias[go];
#pragma unroll
            for (int r = 0; r < 4; ++r) {
                int node = gm + r;
                if (node < n_nodes)
                    out[(size_t)node * OUT_FEATS + go] = acc[mi][ni][r] + b;
            }
        }
    }
}

extern "C" void kernel_launch(void* const* d_in, const int* in_sizes, int n_in,
                              void* d_out, int out_size, void* d_ws, size_t ws_size,
                              hipStream_t stream) {
    const float* feat = (const float*)d_in[0];
    const float* tkv  = (const float*)d_in[1];
    const int*   tki  = (const int*)d_in[2];
    const int*   row  = (const int*)d_in[3];
    const int*   col  = (const int*)d_in[4];
    const float* Wn   = (const float*)d_in[6];
    const float* Ws   = (const float*)d_in[7];
    const float* bias = (const float*)d_in[8];
    float* out = (float*)d_out;

    int n_nodes = in_sizes[5];
    int n_edges = in_sizes[3];

    // ws layout: xsp bf16 [N,128] | Acat bf16 [N,256] | WT bf16 [256,256] | indptr [N+1]
    unsigned short* xsp  = (unsigned short*)d_ws;
    unsigned short* Acat = xsp + (size_t)n_nodes * IN_FEATS;
    unsigned short* WT   = Acat + (size_t)n_nodes * KTOT;
    int* indptr = (int*)(WT + (size_t)OUT_FEATS * KTOT);

    k_scatter<<<(n_nodes + 3) / 4, 256, 0, stream>>>(tkv, tki, feat, xsp, Acat, n_nodes);
    k_weights<<<256, 256, 0, stream>>>(Wn, Ws, WT);
    k_indptr<<<(n_edges + 255) / 256, 256, 0, stream>>>(row, indptr, n_nodes, n_edges);
    k_aggregate<<<(n_nodes + 3) / 4, 256, 0, stream>>>(xsp, indptr, col, Acat, n_nodes);
    k_gemm<<<(n_nodes + BM - 1) / BM, 512, 0, stream>>>(Acat, WT, bias, out, n_nodes);
}

// Round 6
// 282.005 us; speedup vs baseline: 1.5258x; 1.0331x over previous
//
#include <hip/hip_runtime.h>
#include <stdint.h>

#define IN_FEATS 128
#define OUT_FEATS 256
#define TOPK 32
#define BM 128
#define BN 256     /* full N in one block: A-tile staged exactly once */
#define BK 64      /* K-step: 64 bf16 = 128 B row = 8x 16B chunks */
#define KTOT 256

typedef float f32x4 __attribute__((ext_vector_type(4)));
typedef short bf16x8 __attribute__((ext_vector_type(8)));

__device__ __forceinline__ unsigned short f2bf(float x) {
    unsigned u = __float_as_uint(x);
    u += 0x7FFFu + ((u >> 16) & 1u);   // round-to-nearest-even
    return (unsigned short)(u >> 16);
}

// async 16B global -> LDS (linear dest: wave-uniform base + lane*16)
__device__ __forceinline__ void gload16(const void* g, void* l) {
    __builtin_amdgcn_global_load_lds(
        (const __attribute__((address_space(1))) unsigned*)g,
        (__attribute__((address_space(3))) unsigned*)l, 16, 0, 0);
}

// K_prep: three independent prep stages merged into ONE dispatch so they run
// CONCURRENTLY instead of as 3 serialized launches (scatter ~20us + weights
// ~2us + indptr ~8us + 2 launch gaps). Branch is block-uniform.
//   blocks [0, nb_sc):            top-k scatter -> xsp bf16 [N,128]
//                                 + feat f32->bf16 into Acat[:,128:256]
//   blocks [nb_sc, nb_sc+256):    W^T bf16 [256][256] build
//   blocks [nb_sc+256, ...):      indptr from sorted row[]
// (round-4 lesson kept: indptr as parallel streaming writes, NOT per-wave
//  binary search — 42 dependent loads/wave cost ~150us.)
__global__ __launch_bounds__(256) void k_prep(
    const float* __restrict__ vals, const int* __restrict__ idxs,
    const float* __restrict__ feat, const int* __restrict__ row,
    const float* __restrict__ Wn, const float* __restrict__ Ws,
    unsigned short* __restrict__ xsp, unsigned short* __restrict__ Acat,
    unsigned short* __restrict__ WT, int* __restrict__ indptr,
    int n_nodes, int n_edges, int nb_sc) {
    __shared__ float lds[4 * IN_FEATS];
    int t = threadIdx.x;
    int b = blockIdx.x;

    if (b < nb_sc) {
        // ---- scatter: 4 nodes/block, LDS atomic accumulate (dup idx .add) ----
        int n0 = b * 4;
        lds[t] = 0.f;
        lds[t + 256] = 0.f;
        __syncthreads();
        if (t < 4 * TOPK) {
            int h = t >> 5;          // which of the 4 nodes
            int k = t & 31;
            int n = n0 + h;
            if (n < n_nodes) {
                float v = vals[(size_t)n * TOPK + k];
                int ix = idxs[(size_t)n * TOPK + k] & 127;
                atomicAdd(&lds[h * IN_FEATS + ix], v);
            }
        }
        __syncthreads();
        // 64 threads per node, 2 consecutive feats each -> packed u32 stores
        int h2 = t >> 6;
        int f2 = (t & 63) * 2;
        int n = n0 + h2;
        if (n < n_nodes) {
            unsigned lo = f2bf(lds[h2 * IN_FEATS + f2]);
            unsigned hi = f2bf(lds[h2 * IN_FEATS + f2 + 1]);
            *(unsigned*)(xsp + (size_t)n * IN_FEATS + f2) = lo | (hi << 16);
            float2 fv = *(const float2*)(feat + (size_t)n * IN_FEATS + f2);
            unsigned pk = (unsigned)f2bf(fv.x) | ((unsigned)f2bf(fv.y) << 16);
            *(unsigned*)(Acat + (size_t)n * KTOT + IN_FEATS + f2) = pk;
        }
        return;
    }
    b -= nb_sc;
    if (b < 256) {
        // ---- weights: WT[n][k], concat K = [W_neigh; W_self] ----
        int idx = b * 256 + t;       // 0..65535
        int n = idx >> 8;
        int k = idx & 255;
        float v = (k < IN_FEATS) ? Wn[(size_t)k * OUT_FEATS + n]
                                 : Ws[(size_t)(k - IN_FEATS) * OUT_FEATS + n];
        WT[idx] = f2bf(v);
        return;
    }
    b -= 256;
    // ---- indptr: edge-parallel gap-range writes ----
    int e = b * 256 + t;
    if (e >= n_edges) return;
    int r = row[e];
    int rp = (e == 0) ? -1 : row[e - 1];
    for (int x = rp + 1; x <= r; ++x) indptr[x] = e;
    if (e == n_edges - 1)
        for (int x = r + 1; x <= n_nodes; ++x) indptr[x] = n_edges;
}

// K2: mean aggregation -> Acat[node][0:128]. One wave per node, 4 nodes/block.
// lane = eg*16 + fi: 16 lanes x 16B cover one bf16 feature row; 4 edge groups
// x 4-deep unroll -> 16 dense-row gathers in flight per wave (avg degree 16).
// Register accumulate only -- no LDS atomics (round-2 lesson: LDS scatter-add
// serializes 4x worse than the extra gather bytes cost).
__global__ __launch_bounds__(256) void k_aggregate(
    const unsigned short* __restrict__ xsp,
    const int* __restrict__ indptr, const int* __restrict__ col,
    unsigned short* __restrict__ Acat, int n_nodes) {
    int t = threadIdx.x;
    int node = blockIdx.x * 4 + (t >> 6);
    if (node >= n_nodes) return;
    int lane = t & 63;
    int eg = lane >> 4, fi = lane & 15;
    int e0 = indptr[node], e1 = indptr[node + 1];

    float acc[8] = {0.f, 0.f, 0.f, 0.f, 0.f, 0.f, 0.f, 0.f};
    int elast = (e1 > e0) ? (e1 - 1) : e0;
    for (int base = e0; base < e1; base += 16) {
        float s[4];
        int c[4];
        uint4 u[4];
#pragma unroll
        for (int j = 0; j < 4; ++j) {
            int ee = base + j * 4 + eg;
            s[j] = (ee < e1) ? 1.f : 0.f;
            c[j] = col[ee < elast ? ee : elast];
        }
#pragma unroll
        for (int j = 0; j < 4; ++j)
            u[j] = *(const uint4*)(xsp + (size_t)c[j] * IN_FEATS + fi * 8);
#pragma unroll
        for (int j = 0; j < 4; ++j) {
            unsigned p[4] = {u[j].x, u[j].y, u[j].z, u[j].w};
#pragma unroll
            for (int i = 0; i < 4; ++i) {
                acc[2 * i]     = fmaf(s[j], __uint_as_float(p[i] << 16), acc[2 * i]);
                acc[2 * i + 1] = fmaf(s[j], __uint_as_float(p[i] & 0xFFFF0000u), acc[2 * i + 1]);
            }
        }
    }
    // reduce across the 4 edge subgroups (stride 16, 32)
#pragma unroll
    for (int i = 0; i < 8; ++i) {
        acc[i] += __shfl_down(acc[i], 16, 64);
        acc[i] += __shfl_down(acc[i], 32, 64);
    }
    if (eg == 0) {
        int cnt = e1 - e0;
        float inv = 1.0f / (float)(cnt > 0 ? cnt : 1);  // == 1/max(deg,1)
        unsigned o[4];
#pragma unroll
        for (int i = 0; i < 4; ++i) {
            unsigned lo = f2bf(acc[2 * i] * inv);
            unsigned hi = f2bf(acc[2 * i + 1] * inv);
            o[i] = lo | (hi << 16);
        }
        *(uint4*)(Acat + (size_t)node * KTOT + fi * 8) = *(uint4*)&o[0];
    }
}

// K3: rst = Acat @ WT^T + bias.  M=n_nodes, K=256, N=256, all-bf16 A/B.
// BM=128 x BN=256 (full N per block -> A staged exactly once). 512 threads =
// 8 waves in a 2x4 grid, each wave a 64x64 output tile of 16x16x32 MFMAs.
// global_load_lds width-16 staging, LDS LINEAR (required by gload_lds);
// bank spread via chunk swizzle q ^= (row&7) applied identically to global
// SOURCE and ds_read (rule #21).
__global__ __launch_bounds__(512) void k_gemm(
    const unsigned short* __restrict__ Acat,  // [N,256] bf16
    const unsigned short* __restrict__ WT,    // [256][256] bf16, WT[n][k]
    const float* __restrict__ bias,
    float* __restrict__ out, int n_nodes) {
    __shared__ __align__(16) unsigned short Ash[BM * BK];  // 16 KB
    __shared__ __align__(16) unsigned short Bsh[BN * BK];  // 32 KB
    int t = threadIdx.x;
    int m0 = blockIdx.x * BM;
    int lane = t & 63;
    int w = t >> 6;           // 0..7
    int wr = w >> 2, wc = w & 3;
    int lrow = lane & 15, quad = lane >> 4;

    f32x4 acc[4][4];
#pragma unroll
    for (int i = 0; i < 4; ++i)
#pragma unroll
        for (int j = 0; j < 4; ++j)
            acc[i][j] = (f32x4){0.f, 0.f, 0.f, 0.f};

    for (int kk = 0; kk < KTOT; kk += BK) {
        // ---- stage A (1024 chunks, 2/thread) and B (2048 chunks, 4/thread) ----
#pragma unroll
        for (int p = 0; p < 2; ++p) {
            int c = p * 512 + t;
            int rowi = c >> 3;
            int q = (c & 7) ^ (rowi & 7);    // inverse-swizzled global source
            int nodeA = m0 + rowi;
            if (nodeA >= n_nodes) nodeA = n_nodes - 1;   // clamp, in-bounds read
            gload16(Acat + (size_t)nodeA * KTOT + kk + q * 8, &Ash[(size_t)c * 8]);
        }
#pragma unroll
        for (int p = 0; p < 4; ++p) {
            int c = p * 512 + t;
            int rowi = c >> 3;               // 0..255 = global n
            int q = (c & 7) ^ (rowi & 7);
            gload16(WT + (size_t)rowi * KTOT + kk + q * 8, &Bsh[(size_t)c * 8]);
        }
        __syncthreads();

#pragma unroll
        for (int ks = 0; ks < 2; ++ks) {     // two 16x16x32 K-substeps per BK=64
            bf16x8 af[4], bfr[4];
#pragma unroll
            for (int mi = 0; mi < 4; ++mi) {
                int r = wr * 64 + mi * 16 + lrow;
                int q = (ks * 4 + quad) ^ (r & 7);       // swizzled read
                af[mi] = *(const bf16x8*)&Ash[(r * 8 + q) * 8];
            }
#pragma unroll
            for (int ni = 0; ni < 4; ++ni) {
                int r = wc * 64 + ni * 16 + lrow;        // 0..255
                int q = (ks * 4 + quad) ^ (r & 7);
                bfr[ni] = *(const bf16x8*)&Bsh[(r * 8 + q) * 8];
            }
#pragma unroll
            for (int mi = 0; mi < 4; ++mi)
#pragma unroll
                for (int ni = 0; ni < 4; ++ni)
                    acc[mi][ni] = __builtin_amdgcn_mfma_f32_16x16x32_bf16(
                        af[mi], bfr[ni], acc[mi][ni], 0, 0, 0);
        }
        __syncthreads();
    }

    // epilogue: C/D layout col=lane&15, row=quad*4+reg
#pragma unroll
    for (int mi = 0; mi < 4; ++mi) {
        int gm = m0 + wr * 64 + mi * 16 + quad * 4;
#pragma unroll
        for (int ni = 0; ni < 4; ++ni) {
            int go = wc * 64 + ni * 16 + lrow;
            float b = bias[go];
#pragma unroll
            for (int r = 0; r < 4; ++r) {
                int node = gm + r;
                if (node < n_nodes)
                    out[(size_t)node * OUT_FEATS + go] = acc[mi][ni][r] + b;
            }
        }
    }
}

extern "C" void kernel_launch(void* const* d_in, const int* in_sizes, int n_in,
                              void* d_out, int out_size, void* d_ws, size_t ws_size,
                              hipStream_t stream) {
    const float* feat = (const float*)d_in[0];
    const float* tkv  = (const float*)d_in[1];
    const int*   tki  = (const int*)d_in[2];
    const int*   row  = (const int*)d_in[3];
    const int*   col  = (const int*)d_in[4];
    const float* Wn   = (const float*)d_in[6];
    const float* Ws   = (const float*)d_in[7];
    const float* bias = (const float*)d_in[8];
    float* out = (float*)d_out;

    int n_nodes = in_sizes[5];
    int n_edges = in_sizes[3];

    // ws layout: xsp bf16 [N,128] | Acat bf16 [N,256] | WT bf16 [256,256] | indptr [N+1]
    unsigned short* xsp  = (unsigned short*)d_ws;
    unsigned short* Acat = xsp + (size_t)n_nodes * IN_FEATS;
    unsigned short* WT   = Acat + (size_t)n_nodes * KTOT;
    int* indptr = (int*)(WT + (size_t)OUT_FEATS * KTOT);

    int nb_sc = (n_nodes + 3) / 4;
    int nb_ip = (n_edges + 255) / 256;
    int nb_prep = nb_sc + 256 + nb_ip;
    k_prep<<<nb_prep, 256, 0, stream>>>(tkv, tki, feat, row, Wn, Ws,
                                        xsp, Acat, WT, indptr,
                                        n_nodes, n_edges, nb_sc);
    k_aggregate<<<(n_nodes + 3) / 4, 256, 0, stream>>>(xsp, indptr, col, Acat, n_nodes);
    k_gemm<<<(n_nodes + BM - 1) / BM, 512, 0, stream>>>(Acat, WT, bias, out, n_nodes);
}